// Round 9
// baseline (2402.867 us; speedup 1.0000x reference)
//
#include <hip/hip_runtime.h>
#include <hip/hip_bf16.h>
#include <stdint.h>

#define B_ 2
#define L_ 2048
#define D_ 768
#define H_ 12
#define F_ 3072
#define NL_ 12
#define K_ 128
#define G_ 16
#define HD_ 64
#define CPG_ 48            // D_/G_
#define M_TOK (B_*L_)      // 4096
#define SCALE_ 0.125f      // HD^-0.5

typedef __hip_bfloat16 bf16;
typedef __bf16 bf16x8 __attribute__((ext_vector_type(8)));
typedef float f32x4 __attribute__((ext_vector_type(4)));

__device__ __forceinline__ void gload16(const void* g, void* l) {
  __builtin_amdgcn_global_load_lds((const __attribute__((address_space(1))) void*)g,
                                   (__attribute__((address_space(3))) void*)l, 16, 0, 0);
}

// ---------------------------------------------------------------- conv weight pre-transpose
// pcw f32 [768][48][128] -> wT2 bf16 [g][kk][d(48)][ci(64, zero-pad)]
__global__ __launch_bounds__(256) void convw_kernel(const float* __restrict__ w,
                                                    bf16* __restrict__ wT2) {
  int idx = blockIdx.x * 256 + threadIdx.x;        // 16*128*48*64
  int ci = idx & 63;
  int row = idx >> 6;
  int d = row % 48;
  int t2 = row / 48;
  int kk = t2 & 127;
  int g = t2 >> 7;
  float v = (ci < 48) ? w[(((size_t)(g * 48 + d) * 48) + ci) * 128 + kk] : 0.f;
  wT2[idx] = __float2bfloat16(v);
}

// ---------------------------------------------------------------- conv via MFMA v2
// l-tile 128, win 128B swizzled rows, XCD swizzle (2 g per XCD)
__global__ __launch_bounds__(256) void conv_mfma(const float* __restrict__ x,
                                                 const bf16* __restrict__ wT2,
                                                 const float* __restrict__ bias,
                                                 float* __restrict__ out) {
  int flat = blockIdx.x;                 // 512 blocks
  int wgid = (flat & 7) * 64 + (flat >> 3);
  const int g = wgid >> 5;               // 0..15 (2 per XCD)
  int rem = wgid & 31;
  const int l0 = (rem & 15) * 128;
  const int b = rem >> 4;

  const int tid = threadIdx.x, w = tid >> 6, lane = tid & 63;
  const int c15 = lane & 15, g4 = lane >> 4;
  __shared__ __align__(16) bf16 win[256 * 64];    // 32 KB, XOR-swizzled 128B rows
  __shared__ __align__(16) bf16 Wl[2 * 48 * 64];  // 12 KB

  // stage x window: one row per thread, rows l0-64 .. l0+191
  {
    int lg = l0 - 64 + tid;
    char* dst = (char*)win + tid * 128;
    int swr = (tid & 7) << 4;
    uint4 z4 = {0u, 0u, 0u, 0u};
    if ((unsigned)lg < 2048u) {
      const float* srow = x + ((size_t)(b * 2048 + lg) * 768 + g * 48);
#pragma unroll
      for (int c = 0; c < 6; ++c) {
        float4 v0 = *(const float4*)(srow + c * 8);
        float4 v1 = *(const float4*)(srow + c * 8 + 4);
        union { bf16 h[8]; uint4 u; } uu;
        uu.h[0] = __float2bfloat16(v0.x); uu.h[1] = __float2bfloat16(v0.y);
        uu.h[2] = __float2bfloat16(v0.z); uu.h[3] = __float2bfloat16(v0.w);
        uu.h[4] = __float2bfloat16(v1.x); uu.h[5] = __float2bfloat16(v1.y);
        uu.h[6] = __float2bfloat16(v1.z); uu.h[7] = __float2bfloat16(v1.w);
        *(uint4*)(dst + ((c * 16) ^ swr)) = uu.u;
      }
    } else {
#pragma unroll
      for (int c = 0; c < 6; ++c) *(uint4*)(dst + ((c * 16) ^ swr)) = z4;
    }
    *(uint4*)(dst + (96 ^ swr)) = z4;
    *(uint4*)(dst + (112 ^ swr)) = z4;
  }
  __syncthreads();

  f32x4 acc[2][3];
  const f32x4 vzero = {0.f, 0.f, 0.f, 0.f};
#pragma unroll
  for (int i = 0; i < 2; ++i)
#pragma unroll
    for (int j = 0; j < 3; ++j) acc[i][j] = vzero;

  const char* wbase = (const char*)wT2 + (size_t)g * 128 * 48 * 128;

  for (int kp = 0; kp < 64; ++kp) {
#pragma unroll
    for (int i = 0; i < 3; ++i) {
      int coff = w * 3072 + i * 1024;
      int c = coff + (lane << 4);
      int row96 = c >> 7;
      int s = row96 / 48;
      int d = row96 - s * 48;
      int cb2 = c & 127;
      gload16(wbase + ((size_t)((2 * kp + s) * 48 + d)) * 128 + (cb2 ^ ((d & 7) << 4)),
              (char*)Wl + coff);
    }
    __syncthreads();
#pragma unroll
    for (int s = 0; s < 2; ++s) {
      int kk = 2 * kp + s;
#pragma unroll
      for (int cb = 0; cb < 2; ++cb) {
        int a0r = w * 16 + c15 + kk;
        int a1r = 64 + a0r;
        bf16x8 a0 = *(const bf16x8*)((const char*)win + a0r * 128 + ((cb * 64 + g4 * 16) ^ ((a0r & 7) << 4)));
        bf16x8 a1 = *(const bf16x8*)((const char*)win + a1r * 128 + ((cb * 64 + g4 * 16) ^ ((a1r & 7) << 4)));
#pragma unroll
        for (int ct = 0; ct < 3; ++ct) {
          int d = ct * 16 + c15;
          bf16x8 bfrag = *(const bf16x8*)((const char*)Wl + s * 6144 + d * 128 +
                                          ((cb * 64 + g4 * 16) ^ ((d & 7) << 4)));
          acc[0][ct] = __builtin_amdgcn_mfma_f32_16x16x32_bf16(a0, bfrag, acc[0][ct], 0, 0, 0);
          acc[1][ct] = __builtin_amdgcn_mfma_f32_16x16x32_bf16(a1, bfrag, acc[1][ct], 0, 0, 0);
        }
      }
    }
    __syncthreads();
  }

#pragma unroll
  for (int ls = 0; ls < 2; ++ls)
#pragma unroll
    for (int ct = 0; ct < 3; ++ct) {
      int dg = g * 48 + ct * 16 + c15;
      float bv = bias[dg];
#pragma unroll
      for (int r = 0; r < 4; ++r) {
        int l = l0 + ls * 64 + w * 16 + g4 * 4 + r;
        size_t idx = (size_t)(b * 2048 + l) * 768 + dg;
        float vv = acc[ls][ct][r] + bv;
        vv = 0.5f * vv * (1.0f + erff(vv * 0.70710678f));
        out[idx] = x[idx] + vv;
      }
    }
}

// ---------------------------------------------------------------- layernorm: wave-per-row
__global__ __launch_bounds__(256) void ln_kernel(const float* __restrict__ a,
                                                 const float* __restrict__ r,
                                                 const float* __restrict__ g,
                                                 const float* __restrict__ be,
                                                 float* __restrict__ out,
                                                 bf16* __restrict__ outb) {
  int w = threadIdx.x >> 6, lane = threadIdx.x & 63;
  size_t row = (size_t)blockIdx.x * 4 + w;
  const float* ar = a + row * 768;
  const float* rr = r ? r + row * 768 : nullptr;
  float4 v[3];
  float s = 0.f;
#pragma unroll
  for (int i = 0; i < 3; ++i) {
    int c = lane * 4 + i * 256;
    float4 vv = *(const float4*)(ar + c);
    if (rr) {
      float4 rv = *(const float4*)(rr + c);
      vv.x += rv.x; vv.y += rv.y; vv.z += rv.z; vv.w += rv.w;
    }
    v[i] = vv;
    s += vv.x + vv.y + vv.z + vv.w;
  }
#pragma unroll
  for (int st = 1; st < 64; st <<= 1) s += __shfl_xor(s, st);
  float mean = s * (1.0f / 768.0f);
  float s2 = 0.f;
#pragma unroll
  for (int i = 0; i < 3; ++i) {
    float dx = v[i].x - mean, dy = v[i].y - mean, dz = v[i].z - mean, dw = v[i].w - mean;
    s2 += dx * dx + dy * dy + dz * dz + dw * dw;
  }
#pragma unroll
  for (int st = 1; st < 64; st <<= 1) s2 += __shfl_xor(s2, st);
  float rstd = rsqrtf(s2 * (1.0f / 768.0f) + 1e-5f);
#pragma unroll
  for (int i = 0; i < 3; ++i) {
    int c = lane * 4 + i * 256;
    float4 gv = *(const float4*)(g + c);
    float4 bv = *(const float4*)(be + c);
    float4 ov;
    ov.x = (v[i].x - mean) * rstd * gv.x + bv.x;
    ov.y = (v[i].y - mean) * rstd * gv.y + bv.y;
    ov.z = (v[i].z - mean) * rstd * gv.z + bv.z;
    ov.w = (v[i].w - mean) * rstd * gv.w + bv.w;
    *(float4*)(out + row * 768 + c) = ov;
    if (outb) {
      union { bf16 h[4]; uint2 u; } pk;
      pk.h[0] = __float2bfloat16(ov.x); pk.h[1] = __float2bfloat16(ov.y);
      pk.h[2] = __float2bfloat16(ov.z); pk.h[3] = __float2bfloat16(ov.w);
      *(uint2*)(outb + row * 768 + c) = pk.u;
    }
  }
}

// ---------------------------------------------------------------- fused per-layer weight prep
// one dispatch: wqkv castT (1728 tiles) + wo (576) + w1 (2304) + w2 (2304) + bias concat (9)
__global__ __launch_bounds__(256) void prep_weights(const float* __restrict__ wq,
                                                    const float* __restrict__ wk,
                                                    const float* __restrict__ wv,
                                                    const float* __restrict__ wo,
                                                    const float* __restrict__ w1,
                                                    const float* __restrict__ w2,
                                                    const float* __restrict__ bq_,
                                                    const float* __restrict__ bk_,
                                                    const float* __restrict__ bv_,
                                                    bf16* __restrict__ wqkvb,
                                                    bf16* __restrict__ wob,
                                                    bf16* __restrict__ w1b,
                                                    bf16* __restrict__ w2b,
                                                    float* __restrict__ bqkv) {
  __shared__ float t[32][33];
  int tid = threadIdx.x;
  int tx = tid & 31, ty = tid >> 5;
  int blk = blockIdx.x;
  if (blk >= 6912) {
    int i = (blk - 6912) * 256 + tid;
    if (i < 2304) bqkv[i] = (i < 768) ? bq_[i] : (i < 1536) ? bk_[i - 768] : bv_[i - 1536];
    return;
  }
  if (blk < 1728) {                       // wqkv: dst[2304][768]
    int n0 = (blk % 72) * 32, k0 = (blk / 72) * 32;
    const float* src = (n0 < 768) ? wq : (n0 < 1536) ? wk : wv;
    int nn = (n0 >= 1536) ? (n0 - 1536) : (n0 >= 768 ? n0 - 768 : n0);
#pragma unroll
    for (int i = 0; i < 32; i += 8) t[ty + i][tx] = src[(size_t)(k0 + ty + i) * 768 + nn + tx];
    __syncthreads();
#pragma unroll
    for (int i = 0; i < 32; i += 8)
      wqkvb[(size_t)(n0 + ty + i) * 768 + k0 + tx] = __float2bfloat16(t[tx][ty + i]);
    return;
  }
  blk -= 1728;
  if (blk < 576) {                        // wo [768][768] -> wob[768][768]
    int c0 = (blk % 24) * 32, r0 = (blk / 24) * 32;
#pragma unroll
    for (int i = 0; i < 32; i += 8) t[ty + i][tx] = wo[(size_t)(r0 + ty + i) * 768 + c0 + tx];
    __syncthreads();
#pragma unroll
    for (int i = 0; i < 32; i += 8)
      wob[(size_t)(c0 + ty + i) * 768 + r0 + tx] = __float2bfloat16(t[tx][ty + i]);
    return;
  }
  blk -= 576;
  if (blk < 2304) {                       // w1 [768][3072] -> w1b[3072][768]
    int c0 = (blk % 96) * 32, r0 = (blk / 96) * 32;
#pragma unroll
    for (int i = 0; i < 32; i += 8) t[ty + i][tx] = w1[(size_t)(r0 + ty + i) * 3072 + c0 + tx];
    __syncthreads();
#pragma unroll
    for (int i = 0; i < 32; i += 8)
      w1b[(size_t)(c0 + ty + i) * 768 + r0 + tx] = __float2bfloat16(t[tx][ty + i]);
    return;
  }
  blk -= 2304;                            // w2 [3072][768] -> w2b[768][3072]
  {
    int c0 = (blk % 24) * 32, r0 = (blk / 24) * 32;
#pragma unroll
    for (int i = 0; i < 32; i += 8) t[ty + i][tx] = w2[(size_t)(r0 + ty + i) * 768 + c0 + tx];
    __syncthreads();
#pragma unroll
    for (int i = 0; i < 32; i += 8)
      w2b[(size_t)(c0 + ty + i) * 3072 + r0 + tx] = __float2bfloat16(t[tx][ty + i]);
  }
}

// ---------------------------------------------------------------- bf16 MFMA GEMM (+XCD swizzle, optional V->vT epilogue)
template <int BM, int BN, int GELU, int BF16OUT, int VOUT = 0>
__global__ __launch_bounds__(256) void gemm_bf16(const bf16* __restrict__ A,
                                                 const bf16* __restrict__ BT,
                                                 const float* __restrict__ bias,
                                                 void* __restrict__ Cout,
                                                 int N, int Kd,
                                                 bf16* __restrict__ vTout = nullptr) {
  constexpr int WM = BM / 2, MF = WM / 16;
  constexpr int WN = BN / 2, FN = WN / 16;
  __shared__ bf16 As[BM * 64];
  __shared__ bf16 Bs[BN * 64];
  const int tid = threadIdx.x, w = tid >> 6, lane = tid & 63;
  int gx = gridDim.x;
  int flat = blockIdx.x + gx * blockIdx.y;
  int cpx = (gx * gridDim.y) >> 3;
  int sw = (flat & 7) * cpx + (flat >> 3);
  const int bn = sw % gx, bm = sw / gx;
  const int wr = w >> 1, wc = w & 1;
  const int c15 = lane & 15, g4 = lane >> 4;
  const int lrow8 = lane >> 3;
  const int cb = (lane & 7) * 16;

  f32x4 acc[MF][FN];
  const f32x4 vzero = {0.f, 0.f, 0.f, 0.f};
#pragma unroll
  for (int i = 0; i < MF; ++i)
#pragma unroll
    for (int j = 0; j < FN; ++j) acc[i][j] = vzero;

  const char* Ab = (const char*)A;
  const char* Bb = (const char*)BT;

  for (int k0 = 0; k0 < Kd; k0 += 64) {
#pragma unroll
    for (int i = 0; i < BM / 32; ++i) {
      int t = w + 4 * i;
      int row = t * 8 + lrow8;
      gload16(Ab + ((size_t)(bm * BM + row) * Kd + k0) * 2 + (cb ^ ((row & 7) << 4)),
              (char*)As + t * 1024);
    }
#pragma unroll
    for (int i = 0; i < BN / 32; ++i) {
      int t = w + 4 * i;
      int row = t * 8 + lrow8;
      gload16(Bb + ((size_t)(bn * BN + row) * Kd + k0) * 2 + (cb ^ ((row & 7) << 4)),
              (char*)Bs + t * 1024);
    }
    __syncthreads();
    bf16x8 af[MF][2], bfr[FN][2];
#pragma unroll
    for (int kf = 0; kf < 2; ++kf) {
      int kbyte = kf * 64 + g4 * 16;
#pragma unroll
      for (int mf = 0; mf < MF; ++mf) {
        int row = wr * WM + mf * 16 + c15;
        af[mf][kf] = *(const bf16x8*)((const char*)As + row * 128 + (kbyte ^ ((row & 7) << 4)));
      }
#pragma unroll
      for (int fn = 0; fn < FN; ++fn) {
        int row = wc * WN + fn * 16 + c15;
        bfr[fn][kf] = *(const bf16x8*)((const char*)Bs + row * 128 + (kbyte ^ ((row & 7) << 4)));
      }
    }
    __builtin_amdgcn_s_setprio(1);
#pragma unroll
    for (int mf = 0; mf < MF; ++mf)
#pragma unroll
      for (int fn = 0; fn < FN; ++fn) {
        acc[mf][fn] = __builtin_amdgcn_mfma_f32_16x16x32_bf16(af[mf][0], bfr[fn][0], acc[mf][fn], 0, 0, 0);
        acc[mf][fn] = __builtin_amdgcn_mfma_f32_16x16x32_bf16(af[mf][1], bfr[fn][1], acc[mf][fn], 0, 0, 0);
      }
    __builtin_amdgcn_s_setprio(0);
    __syncthreads();
  }
#pragma unroll
  for (int fn = 0; fn < FN; ++fn) {
    int col = bn * BN + wc * WN + fn * 16 + c15;
    float bv = bias[col];
#pragma unroll
    for (int mf = 0; mf < MF; ++mf) {
#pragma unroll
      for (int r = 0; r < 4; ++r) {
        int row = bm * BM + wr * WM + mf * 16 + g4 * 4 + r;
        float vv = acc[mf][fn][r] + bv;
        if (GELU) vv = 0.5f * vv * (1.0f + erff(vv * 0.70710678f));
        if (BF16OUT) {
          if (VOUT && col >= 1536) {      // V slice -> vT[(b*12+h)*64+d][2048]
            int hd2 = col - 1536, hh = hd2 >> 6, dd = hd2 & 63;
            int bb = row >> 11, ll = row & 2047;
            vTout[((size_t)((bb * 12 + hh) * 64 + dd) << 11) + ll] = __float2bfloat16(vv);
          } else {
            ((bf16*)Cout)[(size_t)row * N + col] = __float2bfloat16(vv);
          }
        } else {
          ((float*)Cout)[(size_t)row * N + col] = vv;
        }
      }
    }
  }
}

// ---------------------------------------------------------------- flash attention v4
__global__ __launch_bounds__(256) void attn_mfma(const bf16* __restrict__ qkv,
                                                 const bf16* __restrict__ vT,
                                                 bf16* __restrict__ ob) {
  int bid = blockIdx.x + 32 * (blockIdx.y + 12 * blockIdx.z);
  int wgid = (bid & 7) * 96 + (bid >> 3);
  const int q0 = (wgid & 31) * 64;
  int bh = wgid >> 5;
  const int h = bh % 12, b = bh / 12;

  const int tid = threadIdx.x, w = tid >> 6, lane = tid & 63;
  const int c15 = lane & 15, g4 = lane >> 4;
  const int lrow8 = lane >> 3;
  const int cb = (lane & 7) * 16;
  __shared__ bf16 Kl[2][4096];
  __shared__ bf16 Vl[2][4096];
  __shared__ bf16 Pl[4096];

  const f32x4 vzero = {0.f, 0.f, 0.f, 0.f};
  const char* qp = (const char*)qkv + (((size_t)(b * 2048 + q0 + w * 16 + c15)) * 2304 + h * 64) * 2;
  bf16x8 qa0 = *(const bf16x8*)(qp + g4 * 16);
  bf16x8 qa1 = *(const bf16x8*)(qp + 64 + g4 * 16);

  bf16x8 b_one;
#pragma unroll
  for (int i = 0; i < 8; ++i) b_one[i] = (__bf16)1.0f;

  f32x4 o[4], o5;
#pragma unroll
  for (int i = 0; i < 4; ++i) o[i] = vzero;
  o5 = vzero;
  float m = -1e30f;
  const float SC2 = 0.18033688f;
  const float THR = 11.54f;

  const char* kgb = (const char*)qkv + (((size_t)(b * 2048)) * 2304 + 768 + h * 64) * 2;
  const char* vgb = (const char*)vT + ((size_t)((b * 12 + h) * 64) * 2048) * 2;
  char* Plw = (char*)Pl + w * 2048;

#define STAGE(kt, bufi)                                                                     \
  {                                                                                         \
    char* Kd = (char*)Kl[bufi];                                                             \
    char* Vd = (char*)Vl[bufi];                                                             \
    _Pragma("unroll")                                                                       \
    for (int i = 0; i < 2; ++i) {                                                           \
      int t = w + 4 * i;                                                                    \
      int rr = t * 8 + lrow8;                                                               \
      gload16(kgb + (size_t)((kt) * 64 + rr) * 4608 + (cb ^ ((rr & 7) << 4)), Kd + t * 1024);\
      gload16(vgb + (size_t)rr * 4096 + (size_t)(kt) * 128 + (cb ^ ((rr & 7) << 4)), Vd + t * 1024);\
    }                                                                                       \
  }

  STAGE(0, 0);
  __syncthreads();

  for (int kt = 0; kt < 32; ++kt) {
    int cur = kt & 1;
    if (kt + 1 < 32) STAGE(kt + 1, cur ^ 1);

    const char* Kc = (const char*)Kl[cur];
    const char* Vc = (const char*)Vl[cur];

    f32x4 sc[4];
    __builtin_amdgcn_s_setprio(1);
#pragma unroll
    for (int fn = 0; fn < 4; ++fn) {
      int key = fn * 16 + c15;
      const char* kr = Kc + key * 128;
      int sw = (key & 7) << 4;
      bf16x8 kb0 = *(const bf16x8*)(kr + ((g4 * 16) ^ sw));
      bf16x8 kb1 = *(const bf16x8*)(kr + ((64 + g4 * 16) ^ sw));
      f32x4 s = __builtin_amdgcn_mfma_f32_16x16x32_bf16(kb0, qa0, vzero, 0, 0, 0);
      s = __builtin_amdgcn_mfma_f32_16x16x32_bf16(kb1, qa1, s, 0, 0, 0);
      sc[fn] = s;
    }
    __builtin_amdgcn_s_setprio(0);

    float pm = fmaxf(
        fmaxf(fmaxf(fmaxf(sc[0][0], sc[0][1]), fmaxf(sc[0][2], sc[0][3])),
              fmaxf(fmaxf(sc[1][0], sc[1][1]), fmaxf(sc[1][2], sc[1][3]))),
        fmaxf(fmaxf(fmaxf(sc[2][0], sc[2][1]), fmaxf(sc[2][2], sc[2][3])),
              fmaxf(fmaxf(sc[3][0], sc[3][1]), fmaxf(sc[3][2], sc[3][3]))));
    int ok = (pm * SC2 <= m + THR) ? 1 : 0;

    if (!__all(ok)) {
      float tm = pm;
      tm = fmaxf(tm, __shfl_xor(tm, 16));
      tm = fmaxf(tm, __shfl_xor(tm, 32));
      float mn = fmaxf(m, tm * SC2);
      float alpha = exp2f(m - mn);
      m = mn;
#pragma unroll
      for (int r = 0; r < 4; ++r) {
        float ar = __shfl(alpha, g4 * 4 + r);
        o[0][r] *= ar; o[1][r] *= ar; o[2][r] *= ar; o[3][r] *= ar;
        o5[r] *= ar;
      }
    }

    {
      char* prow = Plw + c15 * 128;
      int swp = (c15 & 7) << 4;
#pragma unroll
      for (int fn = 0; fn < 4; ++fn) {
        union { bf16 hh[4]; uint2 u; } pk;
#pragma unroll
        for (int r = 0; r < 4; ++r)
          pk.hh[r] = __float2bfloat16(exp2f(fmaf(sc[fn][r], SC2, -m)));
        *(uint2*)(prow + ((fn * 32 + g4 * 8) ^ swp)) = pk.u;
      }
    }

    {
      const char* pr = Plw + c15 * 128;
      int sw = (c15 & 7) << 4;
      bf16x8 pa0 = *(const bf16x8*)(pr + ((g4 * 16) ^ sw));
      bf16x8 pa1 = *(const bf16x8*)(pr + ((64 + g4 * 16) ^ sw));
      __builtin_amdgcn_s_setprio(1);
#pragma unroll
      for (int fh = 0; fh < 4; ++fh) {
        int hd = fh * 16 + c15;
        const char* vr = Vc + hd * 128;
        int swv = (hd & 7) << 4;
        bf16x8 vb0 = *(const bf16x8*)(vr + ((g4 * 16) ^ swv));
        bf16x8 vb1 = *(const bf16x8*)(vr + ((64 + g4 * 16) ^ swv));
        o[fh] = __builtin_amdgcn_mfma_f32_16x16x32_bf16(pa0, vb0, o[fh], 0, 0, 0);
        o[fh] = __builtin_amdgcn_mfma_f32_16x16x32_bf16(pa1, vb1, o[fh], 0, 0, 0);
      }
      o5 = __builtin_amdgcn_mfma_f32_16x16x32_bf16(pa0, b_one, o5, 0, 0, 0);
      o5 = __builtin_amdgcn_mfma_f32_16x16x32_bf16(pa1, b_one, o5, 0, 0, 0);
      __builtin_amdgcn_s_setprio(0);
    }
    __syncthreads();
  }
#undef STAGE

#pragma unroll
  for (int r = 0; r < 4; ++r) {
    float inv = 1.0f / o5[r];
    size_t row = (size_t)(b * 2048 + q0 + w * 16 + g4 * 4 + r);
#pragma unroll
    for (int fh = 0; fh < 4; ++fh)
      ob[row * 768 + h * 64 + fh * 16 + c15] = __float2bfloat16(o[fh][r] * inv);
  }
}

// ----------------------------------------------------------------
extern "C" void kernel_launch(void* const* d_in, const int* in_sizes, int n_in,
                              void* d_out, int out_size, void* d_ws, size_t ws_size,
                              hipStream_t stream) {
  const float* x      = (const float*)d_in[0];
  const float* pcw    = (const float*)d_in[1];
  const float* pcb    = (const float*)d_in[2];
  const float* ln0_g  = (const float*)d_in[3];
  const float* ln0_b  = (const float*)d_in[4];
  const float* Wq     = (const float*)d_in[5];
  const float* bq     = (const float*)d_in[6];
  const float* Wk     = (const float*)d_in[7];
  const float* bk     = (const float*)d_in[8];
  const float* Wv     = (const float*)d_in[9];
  const float* bv     = (const float*)d_in[10];
  const float* Wo     = (const float*)d_in[11];
  const float* bo     = (const float*)d_in[12];
  const float* ln1_g  = (const float*)d_in[13];
  const float* ln1_b  = (const float*)d_in[14];
  const float* W1     = (const float*)d_in[15];
  const float* b1     = (const float*)d_in[16];
  const float* W2     = (const float*)d_in[17];
  const float* b2     = (const float*)d_in[18];
  const float* ln2_g  = (const float*)d_in[19];
  const float* ln2_b  = (const float*)d_in[20];

  const size_t MDB = (size_t)M_TOK * D_ * 4;
  char* W = (char*)d_ws;
  float* h    = (float*)W;
  float* tmp  = (float*)(W + MDB);
  char*  big  = W + 2 * MDB;
  bf16*  qkv  = (bf16*)big;
  bf16*  ff   = (bf16*)big;
  bf16*  wT2  = (bf16*)big;
  char* p = W + 2 * MDB + 25165824;
  bf16* h_bf  = (bf16*)p; p += (size_t)M_TOK * D_ * 2;
  bf16* obuf  = (bf16*)p; p += (size_t)M_TOK * D_ * 2;
  bf16* vT    = (bf16*)p; p += (size_t)M_TOK * D_ * 2;
  bf16* wqkvb = (bf16*)p; p += (size_t)2304 * 768 * 2;
  bf16* wob   = (bf16*)p; p += (size_t)768 * 768 * 2;
  bf16* w1b   = (bf16*)p; p += (size_t)3072 * 768 * 2;
  bf16* w2b   = (bf16*)p; p += (size_t)768 * 3072 * 2;
  float* bqkv = (float*)p;

  convw_kernel<<<24576, 256, 0, stream>>>(pcw, wT2);
  conv_mfma<<<512, 256, 0, stream>>>(x, wT2, pcb, tmp);
  ln_kernel<<<M_TOK / 4, 256, 0, stream>>>(tmp, nullptr, ln0_g, ln0_b, h, h_bf);

  for (int l = 0; l < NL_; ++l) {
    const float* wq = Wq + (size_t)l * D_ * D_;
    const float* wk = Wk + (size_t)l * D_ * D_;
    const float* wv = Wv + (size_t)l * D_ * D_;
    const float* wo = Wo + (size_t)l * D_ * D_;
    const float* w1 = W1 + (size_t)l * D_ * F_;
    const float* w2 = W2 + (size_t)l * F_ * D_;

    prep_weights<<<6921, 256, 0, stream>>>(wq, wk, wv, wo, w1, w2,
                                           bq + (size_t)l * D_, bk + (size_t)l * D_, bv + (size_t)l * D_,
                                           wqkvb, wob, w1b, w2b, bqkv);

    gemm_bf16<128, 128, 0, 1, 1><<<dim3(18, 32), 256, 0, stream>>>(h_bf, wqkvb, bqkv, qkv, 2304, 768, vT);
    attn_mfma<<<dim3(32, 12, 2), 256, 0, stream>>>(qkv, vT, obuf);
    gemm_bf16<64, 64, 0, 0><<<dim3(12, 64), 256, 0, stream>>>(obuf, wob, bo + (size_t)l * D_, tmp, 768, 768);
    ln_kernel<<<M_TOK / 4, 256, 0, stream>>>(tmp, h, ln1_g + (size_t)l * D_, ln1_b + (size_t)l * D_, h, h_bf);
    gemm_bf16<128, 128, 1, 1><<<dim3(24, 32), 256, 0, stream>>>(h_bf, w1b, b1 + (size_t)l * F_, ff, 3072, 768);
    gemm_bf16<64, 64, 0, 0><<<dim3(12, 64), 256, 0, stream>>>(ff, w2b, b2 + (size_t)l * D_, tmp, 768, 3072);
    float* out_ln2 = (l == NL_ - 1) ? (float*)d_out : h;
    ln_kernel<<<M_TOK / 4, 256, 0, stream>>>(tmp, h, ln2_g + (size_t)l * D_, ln2_b + (size_t)l * D_, out_ln2, h_bf);
  }
}